// Round 9
// baseline (450.454 us; speedup 1.0000x reference)
//
#include <hip/hip_runtime.h>

#define N_NODES 50000
#define N_EDGES 800000
#define D 64

#define NBUCK 391          // bucket = row >> 7 (128 rows each)
#define CAP   4096         // global region capacity per bucket (mean 2048)

#define A_EPB 8192         // edges per bin block
#define A_BLOCKS ((N_EDGES + A_EPB - 1) / A_EPB)   // 98
#define A_THREADS 512

#define SRT_CAP 3072       // LDS sorted-records capacity (max fill ~2230)
#define NTILE 8            // col tile = col >> 13  (2MB x-slice per tile)
#define NKEY 1024          // key = tile*128 + localrow
#define F_THREADS 512      // 8 waves per fused block

// ---------- init: bucket cursors = region bases (re-run every call) ----------
__global__ __launch_bounds__(512) void initg_kernel(int* __restrict__ gcur)
{
    int b = blockIdx.x * 512 + threadIdx.x;
    if (b < NBUCK) gcur[b] = b * CAP;
}

// ---------- A: block-local counting-sort bin into 391 coarse buckets --------
__global__ __launch_bounds__(A_THREADS) void bin_kernel(
    const int* __restrict__ rows, const int* __restrict__ cols,
    const float* __restrict__ vals, int* __restrict__ gcur,
    int2* __restrict__ buckets)
{
    __shared__ int2 rec[A_EPB];     // 64 KB
    __shared__ int2 srt[A_EPB];     // 64 KB
    __shared__ int cnt[NBUCK];
    __shared__ int lofs[NBUCK];
    __shared__ int lcur[NBUCK];
    __shared__ int bbase[NBUCK];

    const int tid = threadIdx.x;
    const int e0  = blockIdx.x * A_EPB;
    const int n   = min(A_EPB, N_EDGES - e0);

    for (int i = tid; i < NBUCK; i += A_THREADS) cnt[i] = 0;
    __syncthreads();

    for (int i = tid; i < n; i += A_THREADS) {
        int r = rows[e0 + i];
        int c = cols[e0 + i];
        float v = vals[e0 + i];
        rec[i].x = (int)(((unsigned)r << 16) | (unsigned)c);
        rec[i].y = __float_as_int(v);
        atomicAdd(&cnt[r >> 7], 1);
    }
    __syncthreads();

    if (tid < 64) {
        int lane = tid, carry = 0;
        for (int seg = 0; seg < (NBUCK + 63) / 64; ++seg) {
            int j = seg * 64 + lane;
            int v = (j < NBUCK) ? cnt[j] : 0;
            int incl = v;
            for (int off = 1; off < 64; off <<= 1) {
                int u = __shfl_up(incl, off);
                if (lane >= off) incl += u;
            }
            if (j < NBUCK) lofs[j] = carry + incl - v;
            carry += __shfl(incl, 63);
        }
    }
    __syncthreads();

    for (int j = tid; j < NBUCK; j += A_THREADS) {
        int c = cnt[j];
        bbase[j] = c ? atomicAdd(&gcur[j], c) : 0;
        lcur[j]  = lofs[j];
    }
    __syncthreads();

    for (int i = tid; i < n; i += A_THREADS) {
        int2 rv = rec[i];
        int b = ((unsigned)rv.x) >> 23;          // row >> 7
        int p = atomicAdd(&lcur[b], 1);
        srt[p] = rv;
    }
    __syncthreads();

    for (int i = tid; i < n; i += A_THREADS) {
        int2 rv = srt[i];
        int b = ((unsigned)rv.x) >> 23;
        buckets[bbase[b] + (i - lofs[b])] = rv;
    }
}

// ---------- B: fused per-bucket sort + tile-phased gather -------------------
// LDS: srt 24KB + acc 32KB + cnt/lofs/lcur 12KB = 68KB -> 2 blocks/CU.
// Sort key = (coltile<<7)|localrow; gather walks tiles IN ORDER so every
// XCD's L2 holds one 2MB x-slice at a time. acc via ds_add_f32 (lane=feat;
// addr = lr*256B + lane*4 -> 2-way bank alias = free).
__global__ __launch_bounds__(F_THREADS) void sortgather_kernel(
    const float* __restrict__ x, const int2* __restrict__ buckets,
    const int* __restrict__ gcur, const float* __restrict__ ws,
    const int* __restrict__ idx, float* __restrict__ out)
{
    __shared__ int2  srt[SRT_CAP];
    __shared__ float acc[128 * D];
    __shared__ int   cnt[NKEY];
    __shared__ int   lofs[NKEY + 1];
    __shared__ int   lcur[NKEY];

    const int b    = blockIdx.x;
    const int tid  = threadIdx.x;
    const int lane = tid & 63;
    const int w    = tid >> 6;          // wave 0..7
    const int base = b * CAP;
    const int nb   = gcur[b] - base;    // records in this bucket (<= SRT_CAP)

    for (int i = tid; i < NKEY; i += F_THREADS) cnt[i] = 0;
    for (int i = tid; i < 128 * D; i += F_THREADS) acc[i] = 0.f;
    __syncthreads();

    // pass 1: histogram of (tile,row) keys (region is L2/L3-hot, 16KB)
    for (int i = tid; i < nb; i += F_THREADS) {
        int rx  = buckets[base + i].x;
        int key = (((rx & 0xffff) >> 13) << 7) | ((rx >> 16) & 127);
        atomicAdd(&cnt[key], 1);
    }
    __syncthreads();

    // wave 0: exclusive scan cnt -> lofs, sentinel lofs[NKEY]=nb
    if (w == 0) {
        int carry = 0;
        for (int seg = 0; seg < NKEY / 64; ++seg) {
            int j = seg * 64 + lane;
            int v = cnt[j];
            int incl = v;
            for (int off = 1; off < 64; off <<= 1) {
                int u = __shfl_up(incl, off);
                if (lane >= off) incl += u;
            }
            lofs[j] = carry + incl - v;
            carry += __shfl(incl, 63);
        }
        if (lane == 0) lofs[NKEY] = carry;
    }
    __syncthreads();
    for (int i = tid; i < NKEY; i += F_THREADS) lcur[i] = lofs[i];
    __syncthreads();

    // pass 2: scatter records into tile-major LDS order
    for (int i = tid; i < nb; i += F_THREADS) {
        int2 rv = buckets[base + i];
        int key = (((rv.x & 0xffff) >> 13) << 7) | ((rv.x >> 16) & 127);
        int p = atomicAdd(&lcur[key], 1);
        srt[p] = rv;
    }
    __syncthreads();

    // gather: wave w owns rows [w*16, w*16+16); tiles strictly in order
    const int r0 = w * 16;
    for (int t = 0; t < NTILE; ++t) {
        const int segbeg = lofs[t * 128 + r0];
        const int segend = lofs[t * 128 + r0 + 16];
        for (int cb = segbeg; cb < segend; cb += 16) {
            int le = cb + (lane & 15);
            int2 rv = srt[le < segend ? le : segbeg];
            int rx = rv.x;
            int vv = (le < segend) ? rv.y : 0;
#pragma unroll
            for (int k = 0; k < 16; ++k) {
                int sx = __builtin_amdgcn_readlane(rx, k);
                int sv = __builtin_amdgcn_readlane(vv, k);
                int c  = sx & 0xffff;
                int lr = (sx >> 16) & 127;
                float xv = x[(size_t)c * D + lane];
                atomicAdd(&acc[lr * D + lane], __int_as_float(sv) * xv);
            }
        }
    }
    __syncthreads();

    // epilogue: scale + contiguous out write
    const float wgt = ws[idx[0]];
    for (int i = tid; i < 128 * D; i += F_THREADS) {
        int row = b * 128 + (i >> 6);
        if (row < N_NODES) out[(size_t)row * D + (i & 63)] = wgt * acc[i];
    }
}

extern "C" void kernel_launch(void* const* d_in, const int* in_sizes, int n_in,
                              void* d_out, int out_size, void* d_ws, size_t ws_size,
                              hipStream_t stream) {
    const float* x    = (const float*)d_in[0];
    const int*   rows = (const int*)d_in[1];
    const int*   cols = (const int*)d_in[2];
    const float* vals = (const float*)d_in[3];
    const float* ws   = (const float*)d_in[4];
    const int*   idx  = (const int*)d_in[5];
    float*       out  = (float*)d_out;

    // ws layout: [buckets: NBUCK*CAP*8B = 12.8MB][gcur: 512*4B]
    const size_t buckets_bytes = (size_t)NBUCK * CAP * sizeof(int2);

    char* wsb = (char*)d_ws;
    int2* buckets = (int2*)wsb;
    int*  gcur    = (int*)(wsb + buckets_bytes);

    initg_kernel<<<dim3(1), dim3(512), 0, stream>>>(gcur);

    bin_kernel<<<dim3(A_BLOCKS), dim3(A_THREADS), 0, stream>>>(
        rows, cols, vals, gcur, buckets);

    sortgather_kernel<<<dim3(NBUCK), dim3(F_THREADS), 0, stream>>>(
        x, buckets, gcur, ws, idx, out);
}

// Round 10
// 61.687 us; speedup vs baseline: 7.3022x; 7.3022x over previous
//
#include <hip/hip_runtime.h>

#define N_NODES 50000
#define N_EDGES 800000
#define D 64

#define NBUCK 391          // bucket = row >> 7 (128 rows each), rows 0..49999
#define CAP   4096         // region capacity per bucket (mean 2048)

#define A_EPB 8192         // edges per bin block
#define A_BLOCKS ((N_EDGES + A_EPB - 1) / A_EPB)   // 98
#define A_THREADS 512

#define N_RANGES 8
#define ROWS_PER_RANGE 6250
#define GB_PER_RANGE ((ROWS_PER_RANGE + 3) / 4)    // 1563

// ---------- init: bucket cursors = region bases (re-run every call) ----------
__global__ __launch_bounds__(512) void initg_kernel(int* __restrict__ gcur)
{
    int b = blockIdx.x * 512 + threadIdx.x;
    if (b < NBUCK) gcur[b] = b * CAP;
}

// ---------- A: block-local counting-sort bin into 391 coarse buckets --------
__global__ __launch_bounds__(A_THREADS) void bin_kernel(
    const int* __restrict__ rows, const int* __restrict__ cols,
    const float* __restrict__ vals, int* __restrict__ gcur,
    int2* __restrict__ buckets)
{
    __shared__ int2 rec[A_EPB];     // 64 KB
    __shared__ int2 srt[A_EPB];     // 64 KB
    __shared__ int cnt[NBUCK];
    __shared__ int lofs[NBUCK];
    __shared__ int lcur[NBUCK];
    __shared__ int bbase[NBUCK];

    const int tid = threadIdx.x;
    const int e0  = blockIdx.x * A_EPB;
    const int n   = min(A_EPB, N_EDGES - e0);

    for (int i = tid; i < NBUCK; i += A_THREADS) cnt[i] = 0;
    __syncthreads();

    for (int i = tid; i < n; i += A_THREADS) {
        int r = rows[e0 + i];
        int c = cols[e0 + i];
        float v = vals[e0 + i];
        rec[i].x = (int)(((unsigned)r << 16) | (unsigned)c);
        rec[i].y = __float_as_int(v);
        atomicAdd(&cnt[r >> 7], 1);
    }
    __syncthreads();

    if (tid < 64) {
        int lane = tid, carry = 0;
        for (int seg = 0; seg < (NBUCK + 63) / 64; ++seg) {
            int j = seg * 64 + lane;
            int v = (j < NBUCK) ? cnt[j] : 0;
            int incl = v;
            for (int off = 1; off < 64; off <<= 1) {
                int u = __shfl_up(incl, off);
                if (lane >= off) incl += u;
            }
            if (j < NBUCK) lofs[j] = carry + incl - v;
            carry += __shfl(incl, 63);
        }
    }
    __syncthreads();

    for (int j = tid; j < NBUCK; j += A_THREADS) {
        int c = cnt[j];
        bbase[j] = c ? atomicAdd(&gcur[j], c) : 0;
        lcur[j]  = lofs[j];
    }
    __syncthreads();

    for (int i = tid; i < n; i += A_THREADS) {
        int2 rv = rec[i];
        int b = ((unsigned)rv.x) >> 23;          // row >> 7
        int p = atomicAdd(&lcur[b], 1);
        srt[p] = rv;
    }
    __syncthreads();

    for (int i = tid; i < n; i += A_THREADS) {
        int2 rv = srt[i];
        int b = ((unsigned)rv.x) >> 23;
        buckets[bbase[b] + (i - lofs[b])] = rv;
    }
}

// ---------- B: scan 391 bucket totals -> CSR bases ----------
__global__ __launch_bounds__(64) void bscan_kernel(
    const int* __restrict__ gcur, int* __restrict__ cbase,
    int* __restrict__ offsets)
{
    int lane = threadIdx.x, carry = 0;
    for (int seg = 0; seg < (NBUCK + 63) / 64; ++seg) {
        int j = seg * 64 + lane;
        int t = (j < NBUCK) ? (gcur[j] - j * CAP) : 0;
        int incl = t;
        for (int off = 1; off < 64; off <<= 1) {
            int u = __shfl_up(incl, off);
            if (lane >= off) incl += u;
        }
        if (j < NBUCK) cbase[j] = carry + incl - t;
        carry += __shfl(incl, 63);
    }
    if (lane == 0) offsets[N_NODES] = N_EDGES;
}

// ---------- C: per-bucket counting sort -> final CSR + offsets --------------
__global__ __launch_bounds__(256) void sort_kernel(
    const int2* __restrict__ buckets, const int* __restrict__ gcur,
    const int* __restrict__ cbase, int* __restrict__ offsets,
    int2* __restrict__ edges)
{
    __shared__ int2 recs[CAP];      // 32 KB
    __shared__ int2 srt2[CAP];      // 32 KB
    __shared__ int cnt[128];
    __shared__ int lofs[128];
    __shared__ int lcur[128];

    const int b    = blockIdx.x;
    const int tid  = threadIdx.x;
    const int base = b * CAP;
    const int nb   = gcur[b] - base;
    const int cb   = cbase[b];

    if (tid < 128) cnt[tid] = 0;
    __syncthreads();

    for (int i = tid; i < nb; i += 256) {
        int2 rv = buckets[base + i];
        recs[i] = rv;
        atomicAdd(&cnt[(((unsigned)rv.x) >> 16) & 127], 1);
    }
    __syncthreads();

    if (tid < 64) {
        int lane = tid, carry = 0;
        for (int seg = 0; seg < 2; ++seg) {
            int j = seg * 64 + lane;
            int v = cnt[j];
            int incl = v;
            for (int off = 1; off < 64; off <<= 1) {
                int u = __shfl_up(incl, off);
                if (lane >= off) incl += u;
            }
            lofs[j] = carry + incl - v;
            carry += __shfl(incl, 63);
        }
    }
    __syncthreads();

    if (tid < 128) {
        int row = (b << 7) + tid;
        if (row < N_NODES) offsets[row] = cb + lofs[tid];
        lcur[tid] = lofs[tid];
    }
    __syncthreads();

    for (int i = tid; i < nb; i += 256) {
        int2 rv = recs[i];
        int p = atomicAdd(&lcur[(((unsigned)rv.x) >> 16) & 127], 1);
        srt2[p] = rv;
    }
    __syncthreads();

    for (int i = tid; i < nb; i += 256) {
        int2 rv = srt2[i];
        int2 cv;
        cv.x = rv.x & 0xffff;       // col (bucket-local rows strip to 16 bits)
        cv.y = rv.y;                // val bits
        edges[cb + i] = cv;
    }
}

// ---------- D: pull gather, one wave per node, 32-wide chunks ----------
// Lanes 0-31 fetch 32 edge records in one coalesced 256B load; 32 readlane
// broadcasts drive 32 INDEPENDENT x-row loads in flight before the FMA
// chain. Poisson(16) degree -> most nodes finish in a single chunk.
__global__ __launch_bounds__(256) void gather_kernel(
    const float* __restrict__ x, const int2* __restrict__ edges,
    const int* __restrict__ offsets, const float* __restrict__ ws,
    const int* __restrict__ idx, float* __restrict__ out)
{
    const float w = ws[idx[0]];
    const int range = blockIdx.x & (N_RANGES - 1);
    const int j     = blockIdx.x >> 3;
    const int local = j * 4 + (threadIdx.x >> 6);
    if (local >= ROWS_PER_RANGE) return;
    const int node = range * ROWS_PER_RANGE + local;
    const int lane = threadIdx.x & 63;

    const int beg = offsets[node];
    const int end = offsets[node + 1];

    float acc0 = 0.f, acc1 = 0.f;
    for (int base = beg; base < end; base += 32) {
        int le = base + (lane & 31);
        int2 cv = edges[le < end ? le : beg];
        int ci = cv.x;
        int vi = (le < end) ? cv.y : 0;
#pragma unroll
        for (int k = 0; k < 32; ++k) {
            int c = __builtin_amdgcn_readlane(ci, k);
            int v = __builtin_amdgcn_readlane(vi, k);
            float xv = x[(size_t)c * D + lane];
            if (k & 1) acc1 += __int_as_float(v) * xv;
            else       acc0 += __int_as_float(v) * xv;
        }
    }
    out[(size_t)node * D + lane] = w * (acc0 + acc1);
}

extern "C" void kernel_launch(void* const* d_in, const int* in_sizes, int n_in,
                              void* d_out, int out_size, void* d_ws, size_t ws_size,
                              hipStream_t stream) {
    const float* x    = (const float*)d_in[0];
    const int*   rows = (const int*)d_in[1];
    const int*   cols = (const int*)d_in[2];
    const float* vals = (const float*)d_in[3];
    const float* ws   = (const float*)d_in[4];
    const int*   idx  = (const int*)d_in[5];
    float*       out  = (float*)d_out;

    // ws layout: [edges: E*8B][offsets: (N+2)*4B][buckets: NBUCK*CAP*8B][gcur][cbase]
    const size_t edges_bytes   = (size_t)N_EDGES * sizeof(int2);
    const size_t offsets_bytes = (size_t)(N_NODES + 2) * sizeof(int);
    const size_t buckets_bytes = (size_t)NBUCK * CAP * sizeof(int2);
    const size_t gcur_bytes    = 512 * sizeof(int);

    char* wsb = (char*)d_ws;
    int2* edges   = (int2*)wsb;
    int*  offsets = (int*)(wsb + edges_bytes);
    int2* buckets = (int2*)(wsb + edges_bytes + offsets_bytes);
    int*  gcur    = (int*)(wsb + edges_bytes + offsets_bytes + buckets_bytes);
    int*  cbase   = (int*)(wsb + edges_bytes + offsets_bytes + buckets_bytes + gcur_bytes);

    initg_kernel<<<dim3(1), dim3(512), 0, stream>>>(gcur);

    bin_kernel<<<dim3(A_BLOCKS), dim3(A_THREADS), 0, stream>>>(
        rows, cols, vals, gcur, buckets);

    bscan_kernel<<<dim3(1), dim3(64), 0, stream>>>(gcur, cbase, offsets);

    sort_kernel<<<dim3(NBUCK), dim3(256), 0, stream>>>(
        buckets, gcur, cbase, offsets, edges);

    gather_kernel<<<dim3(N_RANGES * GB_PER_RANGE), dim3(256), 0, stream>>>(
        x, edges, offsets, ws, idx, out);
}

// Round 11
// 56.911 us; speedup vs baseline: 7.9150x; 1.0839x over previous
//
#include <hip/hip_runtime.h>

#define N_NODES 50000
#define N_EDGES 800000
#define D 64

#define NBUCK 782          // bucket = row >> 6 (64 rows each)
#define CAP   2048         // global region capacity per bucket (mean 1024, sd 32)
#define SRT_CAP 2048       // LDS sorted-records capacity (= CAP, bulletproof)

#define A_EPB 8192         // edges per bin block
#define A_BLOCKS ((N_EDGES + A_EPB - 1) / A_EPB)   // 98
#define A_THREADS 512

#define F_THREADS 512      // fused: 8 waves, each owns 8 of the 64 rows

typedef unsigned short ushort_t;

// ---------- init: bucket cursors = region bases (re-run every call) ----------
__global__ __launch_bounds__(1024) void initg_kernel(int* __restrict__ gcur)
{
    int b = threadIdx.x;
    if (b < NBUCK) gcur[b] = b * CAP;
}

// ---------- cvt: x (f32) -> xb (bf16, RNE) ----------
__global__ __launch_bounds__(256) void cvt_kernel(
    const float* __restrict__ x, ushort_t* __restrict__ xb)
{
    int i = blockIdx.x * 256 + threadIdx.x;      // group of 4 elements
    float4 v = reinterpret_cast<const float4*>(x)[i];
    ushort4 o;
    unsigned bx;
    bx = __float_as_uint(v.x); o.x = (ushort_t)((bx + 0x7fffu + ((bx >> 16) & 1u)) >> 16);
    bx = __float_as_uint(v.y); o.y = (ushort_t)((bx + 0x7fffu + ((bx >> 16) & 1u)) >> 16);
    bx = __float_as_uint(v.z); o.z = (ushort_t)((bx + 0x7fffu + ((bx >> 16) & 1u)) >> 16);
    bx = __float_as_uint(v.w); o.w = (ushort_t)((bx + 0x7fffu + ((bx >> 16) & 1u)) >> 16);
    reinterpret_cast<ushort4*>(xb)[i] = o;
}

// ---------- A: block-local counting-sort bin into 782 coarse buckets --------
// All global writes are bucket-grouped contiguous runs (issue-coalesced).
__global__ __launch_bounds__(A_THREADS) void bin_kernel(
    const int* __restrict__ rows, const int* __restrict__ cols,
    const float* __restrict__ vals, int* __restrict__ gcur,
    int2* __restrict__ buckets)
{
    __shared__ int2 rec[A_EPB];     // 64 KB
    __shared__ int2 srt[A_EPB];     // 64 KB
    __shared__ int cnt[NBUCK];
    __shared__ int lofs[NBUCK];
    __shared__ int lcur[NBUCK];
    __shared__ int bbase[NBUCK];    // 4*782*4 = 12.5 KB  (total ~140.5 KB)

    const int tid = threadIdx.x;
    const int e0  = blockIdx.x * A_EPB;
    const int n   = min(A_EPB, N_EDGES - e0);

    for (int i = tid; i < NBUCK; i += A_THREADS) cnt[i] = 0;
    __syncthreads();

    for (int i = tid; i < n; i += A_THREADS) {
        int r = rows[e0 + i];
        int c = cols[e0 + i];
        float v = vals[e0 + i];
        rec[i].x = (int)(((unsigned)r << 16) | (unsigned)c);
        rec[i].y = __float_as_int(v);
        atomicAdd(&cnt[r >> 6], 1);
    }
    __syncthreads();

    if (tid < 64) {
        int lane = tid, carry = 0;
        for (int seg = 0; seg < (NBUCK + 63) / 64; ++seg) {
            int j = seg * 64 + lane;
            int v = (j < NBUCK) ? cnt[j] : 0;
            int incl = v;
            for (int off = 1; off < 64; off <<= 1) {
                int u = __shfl_up(incl, off);
                if (lane >= off) incl += u;
            }
            if (j < NBUCK) lofs[j] = carry + incl - v;
            carry += __shfl(incl, 63);
        }
    }
    __syncthreads();

    for (int j = tid; j < NBUCK; j += A_THREADS) {
        int c = cnt[j];
        bbase[j] = c ? atomicAdd(&gcur[j], c) : 0;
        lcur[j]  = lofs[j];
    }
    __syncthreads();

    for (int i = tid; i < n; i += A_THREADS) {
        int2 rv = rec[i];
        int b = ((unsigned)rv.x) >> 22;          // row >> 6
        int p = atomicAdd(&lcur[b], 1);
        srt[p] = rv;
    }
    __syncthreads();

    for (int i = tid; i < n; i += A_THREADS) {
        int2 rv = srt[i];
        int b = ((unsigned)rv.x) >> 22;
        buckets[bbase[b] + (i - lofs[b])] = rv;
    }
}

// ---------- B: fused per-bucket counting sort + register-acc gather ---------
// Block = 64-row bucket. Sort records into LDS grouped by local row, then
// wave w gathers nodes lr = w*8..w*8+7 with the PROVEN structure: 16-edge
// chunk -> lanes 0-15 ds_read records -> readlane broadcasts -> 16
// independent bf16 x-row loads -> FMA chain into register accumulators.
__global__ __launch_bounds__(F_THREADS) void sortgather_kernel(
    const ushort_t* __restrict__ xb, const int2* __restrict__ buckets,
    const int* __restrict__ gcur, const float* __restrict__ ws,
    const int* __restrict__ idx, float* __restrict__ out)
{
    __shared__ int2 srt[SRT_CAP];   // 16 KB
    __shared__ int cnt[64];
    __shared__ int lofs[65];
    __shared__ int lcur[64];

    const int b    = blockIdx.x;
    const int tid  = threadIdx.x;
    const int lane = tid & 63;
    const int w    = tid >> 6;          // wave 0..7
    const int base = b * CAP;
    const int nb   = gcur[b] - base;    // records in this bucket

    if (tid < 64) cnt[tid] = 0;
    __syncthreads();

    // pass 1: histogram of local row (region just written by bin -> L2/L3 hot)
    for (int i = tid; i < nb; i += F_THREADS) {
        int rx = buckets[base + i].x;
        atomicAdd(&cnt[(rx >> 16) & 63], 1);
    }
    __syncthreads();

    // wave 0: 64-wide exclusive scan -> lofs, sentinel
    if (w == 0) {
        int v = cnt[lane];
        int incl = v;
        for (int off = 1; off < 64; off <<= 1) {
            int u = __shfl_up(incl, off);
            if (lane >= off) incl += u;
        }
        lofs[lane] = incl - v;
        if (lane == 63) lofs[64] = incl;
    }
    __syncthreads();
    if (tid < 64) lcur[tid] = lofs[tid];
    __syncthreads();

    // pass 2: scatter into row-grouped LDS order
    for (int i = tid; i < nb; i += F_THREADS) {
        int2 rv = buckets[base + i];
        int p = atomicAdd(&lcur[(rv.x >> 16) & 63], 1);
        srt[p] = rv;
    }
    __syncthreads();

    // gather: wave w owns rows w*8 .. w*8+7 (sequential, register acc each)
    const float wgt = ws[idx[0]];
    for (int q = 0; q < 8; ++q) {
        const int lr   = w * 8 + q;
        const int seg0 = lofs[lr];
        const int seg1 = lofs[lr + 1];
        float acc0 = 0.f, acc1 = 0.f;
        for (int cb = seg0; cb < seg1; cb += 16) {
            int le = cb + (lane & 15);
            int2 cv = srt[le < seg1 ? le : seg0];
            int ci = cv.x;
            int vi = (le < seg1) ? cv.y : 0;
#pragma unroll
            for (int k = 0; k < 16; ++k) {
                int sx = __builtin_amdgcn_readlane(ci, k);
                int sv = __builtin_amdgcn_readlane(vi, k);
                int c  = sx & 0xffff;
                ushort_t u = xb[(size_t)c * D + lane];
                float xv = __uint_as_float(((unsigned)u) << 16);
                if (k & 1) acc1 += __int_as_float(sv) * xv;
                else       acc0 += __int_as_float(sv) * xv;
            }
        }
        const int row = b * 64 + lr;
        if (row < N_NODES)
            out[(size_t)row * D + lane] = wgt * (acc0 + acc1);
    }
}

extern "C" void kernel_launch(void* const* d_in, const int* in_sizes, int n_in,
                              void* d_out, int out_size, void* d_ws, size_t ws_size,
                              hipStream_t stream) {
    const float* x    = (const float*)d_in[0];
    const int*   rows = (const int*)d_in[1];
    const int*   cols = (const int*)d_in[2];
    const float* vals = (const float*)d_in[3];
    const float* ws   = (const float*)d_in[4];
    const int*   idx  = (const int*)d_in[5];
    float*       out  = (float*)d_out;

    // ws layout: [xb: 3.2M*2B = 6.4MB][buckets: NBUCK*CAP*8B = 12.8MB][gcur]
    const size_t xb_bytes      = (size_t)N_NODES * D * sizeof(ushort_t);
    const size_t buckets_bytes = (size_t)NBUCK * CAP * sizeof(int2);

    char* wsb = (char*)d_ws;
    ushort_t* xb      = (ushort_t*)wsb;
    int2*     buckets = (int2*)(wsb + xb_bytes);
    int*      gcur    = (int*)(wsb + xb_bytes + buckets_bytes);

    initg_kernel<<<dim3(1), dim3(1024), 0, stream>>>(gcur);

    cvt_kernel<<<dim3(N_NODES * D / 4 / 256), dim3(256), 0, stream>>>(x, xb);

    bin_kernel<<<dim3(A_BLOCKS), dim3(A_THREADS), 0, stream>>>(
        rows, cols, vals, gcur, buckets);

    sortgather_kernel<<<dim3(NBUCK), dim3(F_THREADS), 0, stream>>>(
        xb, buckets, gcur, ws, idx, out);
}